// Round 4
// baseline (273.151 us; speedup 1.0000x reference)
//
#include <hip/hip_runtime.h>
#include <stdint.h>

typedef unsigned short u16;
typedef unsigned int   u32;

typedef float  f32x4  __attribute__((ext_vector_type(4)));
typedef __bf16 bf16x8 __attribute__((ext_vector_type(8)));

// ---------- helpers ----------
__device__ __forceinline__ u16 f2bf(float f) {
  union { float f; u32 u; } c; c.f = f;
  u32 u = c.u + 0x7fffu + ((c.u >> 16) & 1u);   // RNE; inputs finite
  return (u16)(u >> 16);
}
__device__ __forceinline__ float bf2f(u16 h) {
  union { u32 u; float f; } c; c.u = ((u32)h) << 16;
  return c.f;
}
__device__ __forceinline__ void gll16(const void* g, void* l) {
  __builtin_amdgcn_global_load_lds(
      (const __attribute__((address_space(1))) void*)g,
      (__attribute__((address_space(3))) void*)l, 16, 0, 0);
}
__device__ __forceinline__ bf16x8 cvt8(f32x4 a, f32x4 b) {
  union { u32 w[4]; bf16x8 v; } r;
  r.w[0] = (u32)f2bf(a.x) | ((u32)f2bf(a.y) << 16);
  r.w[1] = (u32)f2bf(a.z) | ((u32)f2bf(a.w) << 16);
  r.w[2] = (u32)f2bf(b.x) | ((u32)f2bf(b.y) << 16);
  r.w[3] = (u32)f2bf(b.z) | ((u32)f2bf(b.w) << 16);
  return r.v;
}

// fused convert for the two weight matrices (blockIdx.y selects which)
__global__ __launch_bounds__(256) void cvt_bf16_w(const float4* __restrict__ s0,
                                                  uint2* __restrict__ d0,
                                                  const float4* __restrict__ s1,
                                                  uint2* __restrict__ d1, int n4) {
  int i = blockIdx.x * 256 + threadIdx.x;
  if (i >= n4) return;
  const float4* s = blockIdx.y ? s1 : s0;
  uint2*        d = blockIdx.y ? d1 : d0;
  float4 v = s[i];
  uint2 o;
  o.x = (u32)f2bf(v.x) | ((u32)f2bf(v.y) << 16);
  o.y = (u32)f2bf(v.z) | ((u32)f2bf(v.w) << 16);
  d[i] = o;
}

// ================= GEMM1: C[M,N](bf16) = A[M,K](fp32) * B[N,K](bf16)^T ======
// A staged as fp32 (x read directly, no pre-convert kernel), converted to bf16
// at frag-read. LDS layouts use a [kc-pair] major arrangement so frag-read row
// stride is 32 B (8 banks) -> 2-way bank aliasing only (free), vs 64 B (4-way)
// in the naive row-major tile. gll chunk->lane maps re-derived to match.
__global__ __launch_bounds__(256, 4)
void gemm1_f32a(const float* __restrict__ A, const u16* __restrict__ B,
                u16* __restrict__ C, int M, int N, int K) {
  __shared__ float As[128 * 32];   // 16 KB: float idx = kc2*1024 + r*8 + kcl*4 + e
  __shared__ u16   Bs[128 * 32];   // 8 KB: u16 idx = kc2*2048 + r*16 + kcl*8 + e
  const int t    = threadIdx.x;
  const int lane = t & 63;
  const int ml   = lane & 15;
  const int q    = lane >> 4;
  const int wave = t >> 6;
  const int wm   = wave >> 1;
  const int wn   = wave & 1;

  // XCD-locality swizzle (gridDim.x == 8)
  const int flat    = blockIdx.y * 8 + blockIdx.x;
  const int xcd     = flat & 7;
  const int slot    = flat >> 3;
  const int per_xcd = gridDim.y >> 3;
  const int mt      = xcd * per_xcd + (slot >> 3);
  const int nt      = slot & 7;
  const int m0      = mt * 128;
  const int n0      = nt * 128;

  f32x4 acc[4][4] = {};

  // staging: row r = t>>1 staged by thread pair (t&1)
  // A fp32: call j stages chunk kc = 2j + (t&1) (4 floats) of row r
  const float* Aga = A + (size_t)(m0 + (t >> 1)) * K + 4 * (t & 1);
  // B bf16: call j stages chunk kc = 2j + (t&1) (8 elems) of row r
  const u16*   Bga = B + (size_t)(n0 + (t >> 1)) * K + 8 * (t & 1);
  const int wb = (t & 192) * 16;  // wave-uniform LDS byte base within a 256-slot group
  char* AsB = (char*)As;
  char* BsB = (char*)Bs;

  for (int k0 = 0; k0 < K; k0 += 32) {
#pragma unroll
    for (int j = 0; j < 4; ++j)
      gll16(Aga + k0 + 8 * j, AsB + j * 4096 + wb);
#pragma unroll
    for (int j = 0; j < 2; ++j)
      gll16(Bga + k0 + 16 * j, BsB + j * 4096 + wb);
    __syncthreads();

    bf16x8 af[4], bfv[4];
#pragma unroll
    for (int i = 0; i < 4; ++i) {
      const int R = wm * 64 + i * 16 + ml;
      f32x4 a = *reinterpret_cast<const f32x4*>(&As[q * 1024 + R * 8]);
      f32x4 b = *reinterpret_cast<const f32x4*>(&As[q * 1024 + R * 8 + 4]);
      af[i] = cvt8(a, b);
    }
#pragma unroll
    for (int i = 0; i < 4; ++i) {
      const int R = wn * 64 + i * 16 + ml;
      bfv[i] = *reinterpret_cast<const bf16x8*>(&Bs[(q >> 1) * 2048 + R * 16 + (q & 1) * 8]);
    }
#pragma unroll
    for (int i = 0; i < 4; ++i)
#pragma unroll
      for (int j = 0; j < 4; ++j)
        acc[i][j] = __builtin_amdgcn_mfma_f32_16x16x32_bf16(af[i], bfv[j], acc[i][j], 0, 0, 0);
    __syncthreads();
  }

  const int rowb = m0 + wm * 64 + q * 4;
  const int colb = n0 + wn * 64 + ml;
#pragma unroll
  for (int i = 0; i < 4; ++i)
#pragma unroll
    for (int j = 0; j < 4; ++j)
#pragma unroll
      for (int r = 0; r < 4; ++r)
        C[(size_t)(rowb + i * 16 + r) * N + (colb + j * 16)] = f2bf(acc[i][j][r]);
}

// ================= GEMM2: C[M,N](fp32) = A[M,K](bf16) * B[N,K](bf16)^T ======
__global__ __launch_bounds__(256, 4)
void gemm2_bf16(const u16* __restrict__ A, const u16* __restrict__ B,
                float* __restrict__ C, int M, int N, int K) {
  __shared__ u16 As[128 * 32];
  __shared__ u16 Bs[128 * 32];
  const int t    = threadIdx.x;
  const int lane = t & 63;
  const int ml   = lane & 15;
  const int q    = lane >> 4;
  const int wave = t >> 6;
  const int wm   = wave >> 1;
  const int wn   = wave & 1;

  const int flat    = blockIdx.y * 8 + blockIdx.x;
  const int xcd     = flat & 7;
  const int slot    = flat >> 3;
  const int per_xcd = gridDim.y >> 3;
  const int mt      = xcd * per_xcd + (slot >> 3);
  const int nt      = slot & 7;
  const int m0      = mt * 128;
  const int n0      = nt * 128;

  f32x4 acc[4][4] = {};

  const u16* Aga = A + (size_t)(m0 + (t >> 1)) * K + 8 * (t & 1);
  const u16* Bga = B + (size_t)(n0 + (t >> 1)) * K + 8 * (t & 1);
  const int wb = (t & 192) * 16;
  char* AsB = (char*)As;
  char* BsB = (char*)Bs;

  for (int k0 = 0; k0 < K; k0 += 32) {
#pragma unroll
    for (int j = 0; j < 2; ++j) {
      gll16(Aga + k0 + 16 * j, AsB + j * 4096 + wb);
      gll16(Bga + k0 + 16 * j, BsB + j * 4096 + wb);
    }
    __syncthreads();

    bf16x8 af[4], bfv[4];
#pragma unroll
    for (int i = 0; i < 4; ++i) {
      const int R = wm * 64 + i * 16 + ml;
      af[i] = *reinterpret_cast<const bf16x8*>(&As[(q >> 1) * 2048 + R * 16 + (q & 1) * 8]);
    }
#pragma unroll
    for (int i = 0; i < 4; ++i) {
      const int R = wn * 64 + i * 16 + ml;
      bfv[i] = *reinterpret_cast<const bf16x8*>(&Bs[(q >> 1) * 2048 + R * 16 + (q & 1) * 8]);
    }
#pragma unroll
    for (int i = 0; i < 4; ++i)
#pragma unroll
      for (int j = 0; j < 4; ++j)
        acc[i][j] = __builtin_amdgcn_mfma_f32_16x16x32_bf16(af[i], bfv[j], acc[i][j], 0, 0, 0);
    __syncthreads();
  }

  const int rowb = m0 + wm * 64 + q * 4;
  const int colb = n0 + wn * 64 + ml;
#pragma unroll
  for (int i = 0; i < 4; ++i)
#pragma unroll
    for (int j = 0; j < 4; ++j)
#pragma unroll
      for (int r = 0; r < 4; ++r)
        C[(size_t)(rowb + i * 16 + r) * N + (colb + j * 16)] = acc[i][j][r];
}

// ---------- analytic Gaussian attention: 13-tap conv along L ----------
__global__ __launch_bounds__(256)
void gauss_conv(const u16* __restrict__ v, u16* __restrict__ att, int L) {
  constexpr float wt[13] = {
    1.5229979744712628e-08f, 3.7266531720786709e-06f, 3.3546262790251185e-04f,
    1.1108996538242306e-02f, 1.3533528323661270e-01f, 6.0653065971263342e-01f,
    1.0f,
    6.0653065971263342e-01f, 1.3533528323661270e-01f, 1.1108996538242306e-02f,
    3.3546262790251185e-04f, 3.7266531720786709e-06f, 1.5229979744712628e-08f
  };
  const int t  = threadIdx.x;
  const int fg = t & 15;
  const int li = t >> 4;
  const int l  = blockIdx.x * 16 + li;
  const int h  = blockIdx.y;
  const int b  = blockIdx.z;
  int c;
  switch (h) {
    case 0: case 5: c = l;     break;
    case 1: case 6: c = l - 1; break;
    case 2: case 7: c = l + 1; break;
    case 3:         c = 0;     break;
    default:        c = L - 1; break;
  }
  const int fbase = h * 128 + fg * 8;
  const u16* vb = v + (size_t)b * L * 1024 + fbase;

  float a[8] = {};
  float Z = 0.f;
#pragma unroll
  for (int d = -6; d <= 6; ++d) {
    int idx = c + d;
    bool ok = (idx >= 0) && (idx < L);
    int ic = idx < 0 ? 0 : (idx >= L ? L - 1 : idx);
    float w = ok ? wt[d + 6] : 0.f;
    Z += w;
    uint4 p = *reinterpret_cast<const uint4*>(vb + (size_t)ic * 1024);
    a[0] = fmaf(w, bf2f((u16)(p.x & 0xffffu)), a[0]);
    a[1] = fmaf(w, bf2f((u16)(p.x >> 16)),     a[1]);
    a[2] = fmaf(w, bf2f((u16)(p.y & 0xffffu)), a[2]);
    a[3] = fmaf(w, bf2f((u16)(p.y >> 16)),     a[3]);
    a[4] = fmaf(w, bf2f((u16)(p.z & 0xffffu)), a[4]);
    a[5] = fmaf(w, bf2f((u16)(p.z >> 16)),     a[5]);
    a[6] = fmaf(w, bf2f((u16)(p.w & 0xffffu)), a[6]);
    a[7] = fmaf(w, bf2f((u16)(p.w >> 16)),     a[7]);
  }
  float inv = 1.0f / Z;
  uint4 o;
  o.x = (u32)f2bf(a[0] * inv) | ((u32)f2bf(a[1] * inv) << 16);
  o.y = (u32)f2bf(a[2] * inv) | ((u32)f2bf(a[3] * inv) << 16);
  o.z = (u32)f2bf(a[4] * inv) | ((u32)f2bf(a[5] * inv) << 16);
  o.w = (u32)f2bf(a[6] * inv) | ((u32)f2bf(a[7] * inv) << 16);
  *reinterpret_cast<uint4*>(att + (size_t)(b * L + l) * 1024 + fbase) = o;
}

// ---------- launch ----------
extern "C" void kernel_launch(void* const* d_in, const int* in_sizes, int n_in,
                              void* d_out, int out_size, void* d_ws, size_t ws_size,
                              hipStream_t stream) {
  const int Bb = 8, L = 2048, E = 1024;
  const int M = Bb * L, N = E, K = E;

  const float* x  = (const float*)d_in[0];
  const float* Wi = (const float*)d_in[1];
  const float* Wo = (const float*)d_in[2];
  float* out = (float*)d_out;

  // ws layout (bf16): [v 32Mi | att 32Mi | wib 2Mi | wob 2Mi]
  size_t offAtt = (size_t)M * E * 2;
  size_t offWi  = offAtt + (size_t)M * E * 2;
  size_t offWo  = offWi + (size_t)E * E * 2;
  size_t need   = offWo + (size_t)E * E * 2;
  if (ws_size < need) return;

  u16* v   = (u16*)d_ws;
  u16* att = (u16*)((char*)d_ws + offAtt);
  u16* wib = (u16*)((char*)d_ws + offWi);
  u16* wob = (u16*)((char*)d_ws + offWo);

  int n4w = E * E / 4;
  cvt_bf16_w<<<dim3(n4w / 256, 2), 256, 0, stream>>>(
      (const float4*)Wi, (uint2*)wib, (const float4*)Wo, (uint2*)wob, n4w);

  dim3 gg(N / 128, M / 128);   // (8, 128) — swizzle in-kernel assumes x==8
  gemm1_f32a<<<gg, 256, 0, stream>>>(x, wib, v, M, N, K);
  gauss_conv<<<dim3(L / 16, 8, Bb), 256, 0, stream>>>(v, att, L);
  gemm2_bf16<<<gg, 256, 0, stream>>>(att, wob, out, M, N, K);
}

// Round 5
// 210.576 us; speedup vs baseline: 1.2972x; 1.2972x over previous
//
#include <hip/hip_runtime.h>
#include <stdint.h>

typedef unsigned short u16;
typedef unsigned int   u32;

typedef float  f32x4  __attribute__((ext_vector_type(4)));
typedef __bf16 bf16x8 __attribute__((ext_vector_type(8)));

// ---------- helpers ----------
__device__ __forceinline__ u16 f2bf(float f) {
  union { float f; u32 u; } c; c.f = f;
  u32 u = c.u + 0x7fffu + ((c.u >> 16) & 1u);   // RNE; inputs finite
  return (u16)(u >> 16);
}
__device__ __forceinline__ float bf2f(u16 h) {
  union { u32 u; float f; } c; c.u = ((u32)h) << 16;
  return c.f;
}
__device__ __forceinline__ void gll16(const void* g, void* l) {
  __builtin_amdgcn_global_load_lds(
      (const __attribute__((address_space(1))) void*)g,
      (__attribute__((address_space(3))) void*)l, 16, 0, 0);
}

// ---------- fused fp32 -> bf16 convert: x, Wi, Wo in ONE dispatch ----------
__global__ __launch_bounds__(256)
void cvt_all(const float4* __restrict__ x,  uint2* __restrict__ xb,  int n4x,
             const float4* __restrict__ wi, uint2* __restrict__ wib,
             const float4* __restrict__ wo, uint2* __restrict__ wob, int n4w) {
  int i = blockIdx.x * 256 + threadIdx.x;
  const float4* s; uint2* d; int j;
  if (i < n4x)            { s = x;  d = xb;  j = i; }
  else if (i < n4x + n4w) { s = wi; d = wib; j = i - n4x; }
  else                    { s = wo; d = wob; j = i - n4x - n4w; }
  float4 v = s[j];
  uint2 o;
  o.x = (u32)f2bf(v.x) | ((u32)f2bf(v.y) << 16);
  o.y = (u32)f2bf(v.z) | ((u32)f2bf(v.w) << 16);
  d[j] = o;
}

// ---------- bf16 NT GEMM: C[M,N] = A[M,K] * B[N,K]^T ----------
// Round-3 structure + BK=64 (16 k-iters, half the barrier drains) and
// XOR-swizzled chunk placement: LDS slot (row r, chunk c) holds global chunk
// c^(r&7) of row r. Swizzle applied on the GLOBAL address side so that
// global_load_lds's lane-contiguous LDS scatter is preserved; frag reads then
// hit 8 lanes per 4-bank group (minimal for b128) by the xor balance.
// Grid must be (8, M/128); XCD swizzle keeps an m-band + all B in one L2.
template <bool OUT_BF16>
__global__ __launch_bounds__(256, 4)
void gemm_nt_bf16(const u16* __restrict__ A, const u16* __restrict__ B,
                  void* __restrict__ Cout, int M, int N, int K) {
  __shared__ u16 As[128 * 64];   // 16 KB each; row stride 64 u16 = 128 B
  __shared__ u16 Bs[128 * 64];
  const int t    = threadIdx.x;
  const int lane = t & 63;
  const int ml   = lane & 15;
  const int q    = lane >> 4;
  const int wave = t >> 6;
  const int wm   = wave >> 1;
  const int wn   = wave & 1;

  // ---- XCD-locality swizzle (bijection; gridDim.x == 8) ----
  const int flat    = blockIdx.y * 8 + blockIdx.x;
  const int xcd     = flat & 7;
  const int slot    = flat >> 3;
  const int per_xcd = gridDim.y >> 3;
  const int mt      = xcd * per_xcd + (slot >> 3);
  const int nt      = slot & 7;
  const int m0      = mt * 128;
  const int n0      = nt * 128;

  f32x4 acc[4][4] = {};

  // staging: thread t, j=0..3 stages chunk id c = t + 256j:
  //   LDS byte = c*16 (row sr=c>>3, slot-chunk c&7); global chunk = (c&7)^(sr&7)
  const int sr = t >> 3;                             // 0..31 (+32j per j)
  const int gk = (((t & 7) ^ (sr & 7)) * 8);         // global k-offset (u16)
  const u16* Ag = A + (size_t)(m0 + sr) * K + gk;
  const u16* Bg = B + (size_t)(n0 + sr) * K + gk;
  const int wb = (t & 192) * 16;                     // wave-uniform byte base
  char* AsB = (char*)As;
  char* BsB = (char*)Bs;

  for (int k0 = 0; k0 < K; k0 += 64) {
#pragma unroll
    for (int j = 0; j < 4; ++j) {
      gll16(Ag + (size_t)(32 * j) * K + k0, AsB + j * 4096 + wb);
      gll16(Bg + (size_t)(32 * j) * K + k0, BsB + j * 4096 + wb);
    }
    __syncthreads();
#pragma unroll
    for (int s = 0; s < 2; ++s) {       // two k=32 sub-steps
      bf16x8 af[4], bfv[4];
#pragma unroll
      for (int i = 0; i < 4; ++i) {
        const int R = wm * 64 + i * 16 + ml;
        af[i] = *reinterpret_cast<const bf16x8*>(
            &As[R * 64 + (((s * 4 + q) ^ (R & 7)) * 8)]);
      }
#pragma unroll
      for (int i = 0; i < 4; ++i) {
        const int R = wn * 64 + i * 16 + ml;
        bfv[i] = *reinterpret_cast<const bf16x8*>(
            &Bs[R * 64 + (((s * 4 + q) ^ (R & 7)) * 8)]);
      }
#pragma unroll
      for (int i = 0; i < 4; ++i)
#pragma unroll
        for (int j = 0; j < 4; ++j)
          acc[i][j] = __builtin_amdgcn_mfma_f32_16x16x32_bf16(af[i], bfv[j], acc[i][j], 0, 0, 0);
    }
    __syncthreads();
  }

  // epilogue: C/D frag row = q*4 + reg, col = lane&15 (verified m89/m91)
  const int rowb = m0 + wm * 64 + q * 4;
  const int colb = n0 + wn * 64 + ml;
#pragma unroll
  for (int i = 0; i < 4; ++i)
#pragma unroll
    for (int j = 0; j < 4; ++j)
#pragma unroll
      for (int r = 0; r < 4; ++r) {
        size_t idx = (size_t)(rowb + i * 16 + r) * N + (colb + j * 16);
        float val = acc[i][j][r];
        if (OUT_BF16) ((u16*)Cout)[idx] = f2bf(val);
        else          ((float*)Cout)[idx] = val;
      }
}

// ---------- analytic Gaussian attention: 13-tap conv along L ----------
__global__ __launch_bounds__(256)
void gauss_conv(const u16* __restrict__ v, u16* __restrict__ att, int L) {
  constexpr float wt[13] = {
    1.5229979744712628e-08f, 3.7266531720786709e-06f, 3.3546262790251185e-04f,
    1.1108996538242306e-02f, 1.3533528323661270e-01f, 6.0653065971263342e-01f,
    1.0f,
    6.0653065971263342e-01f, 1.3533528323661270e-01f, 1.1108996538242306e-02f,
    3.3546262790251185e-04f, 3.7266531720786709e-06f, 1.5229979744712628e-08f
  };
  const int t  = threadIdx.x;
  const int fg = t & 15;
  const int li = t >> 4;
  const int l  = blockIdx.x * 16 + li;
  const int h  = blockIdx.y;             // head: block-uniform
  const int b  = blockIdx.z;
  int c;
  switch (h) {
    case 0: case 5: c = l;     break;
    case 1: case 6: c = l - 1; break;
    case 2: case 7: c = l + 1; break;
    case 3:         c = 0;     break;
    default:        c = L - 1; break;
  }
  const int fbase = h * 128 + fg * 8;
  const u16* vb = v + (size_t)b * L * 1024 + fbase;

  float a[8] = {};
  float Z = 0.f;
#pragma unroll
  for (int d = -6; d <= 6; ++d) {
    int idx = c + d;
    bool ok = (idx >= 0) && (idx < L);
    int ic = idx < 0 ? 0 : (idx >= L ? L - 1 : idx);
    float w = ok ? wt[d + 6] : 0.f;
    Z += w;
    uint4 p = *reinterpret_cast<const uint4*>(vb + (size_t)ic * 1024);
    a[0] = fmaf(w, bf2f((u16)(p.x & 0xffffu)), a[0]);
    a[1] = fmaf(w, bf2f((u16)(p.x >> 16)),     a[1]);
    a[2] = fmaf(w, bf2f((u16)(p.y & 0xffffu)), a[2]);
    a[3] = fmaf(w, bf2f((u16)(p.y >> 16)),     a[3]);
    a[4] = fmaf(w, bf2f((u16)(p.z & 0xffffu)), a[4]);
    a[5] = fmaf(w, bf2f((u16)(p.z >> 16)),     a[5]);
    a[6] = fmaf(w, bf2f((u16)(p.w & 0xffffu)), a[6]);
    a[7] = fmaf(w, bf2f((u16)(p.w >> 16)),     a[7]);
  }
  float inv = 1.0f / Z;
  uint4 o;
  o.x = (u32)f2bf(a[0] * inv) | ((u32)f2bf(a[1] * inv) << 16);
  o.y = (u32)f2bf(a[2] * inv) | ((u32)f2bf(a[3] * inv) << 16);
  o.z = (u32)f2bf(a[4] * inv) | ((u32)f2bf(a[5] * inv) << 16);
  o.w = (u32)f2bf(a[6] * inv) | ((u32)f2bf(a[7] * inv) << 16);
  *reinterpret_cast<uint4*>(att + (size_t)(b * L + l) * 1024 + fbase) = o;
}

// ---------- launch ----------
extern "C" void kernel_launch(void* const* d_in, const int* in_sizes, int n_in,
                              void* d_out, int out_size, void* d_ws, size_t ws_size,
                              hipStream_t stream) {
  const int Bb = 8, L = 2048, E = 1024;
  const int M = Bb * L, N = E, K = E;

  const float* x  = (const float*)d_in[0];
  const float* Wi = (const float*)d_in[1];
  const float* Wo = (const float*)d_in[2];
  float* out = (float*)d_out;

  // ws layout (bf16): [xb 32Mi | v 32Mi | wib 2Mi | wob 2Mi]; att reuses xb
  size_t offV  = (size_t)M * E * 2;
  size_t offWi = offV + (size_t)M * E * 2;
  size_t offWo = offWi + (size_t)E * E * 2;
  size_t need  = offWo + (size_t)E * E * 2;
  if (ws_size < need) return;

  u16* xb  = (u16*)d_ws;
  u16* v   = (u16*)((char*)d_ws + offV);
  u16* wib = (u16*)((char*)d_ws + offWi);
  u16* wob = (u16*)((char*)d_ws + offWo);
  u16* att = xb;  // reuse: conv runs after GEMM1 completes

  int n4x = M * E / 4, n4w = E * E / 4;
  int nblk = (n4x + 2 * n4w) / 256;
  cvt_all<<<nblk, 256, 0, stream>>>((const float4*)x, (uint2*)xb, n4x,
                                    (const float4*)Wi, (uint2*)wib,
                                    (const float4*)Wo, (uint2*)wob, n4w);

  dim3 gg(N / 128, M / 128);   // (8, 128) — swizzle in-kernel assumes x==8
  gemm_nt_bf16<true ><<<gg, 256, 0, stream>>>(xb,  wib, v,   M, N, K);
  gauss_conv<<<dim3(L / 16, 8, Bb), 256, 0, stream>>>(v, att, L);
  gemm_nt_bf16<false><<<gg, 256, 0, stream>>>(att, wob, out, M, N, K);
}